// Round 1
// baseline (3209.836 us; speedup 1.0000x reference)
//
#include <hip/hip_runtime.h>
#include <cstdint>

// Problem constants
#define BB 2
#define TT 5
#define CC 64
#define HH 128
#define WW 128
#define GG 8
#define KKD 9
#define OFFC 144
#define H2 64
#define W2 64
#define TCF 2
#define HW (HH*WW)
#define HW2 (H2*W2)

// ---------------- weight transposes (one-time tiny kernels) ----------------
// w (64,64,3,3) -> wT[(cin*9+k)*64 + oc]
__global__ void wtransD_k(const float* __restrict__ w, float* __restrict__ wT) {
    int idx = blockIdx.x * 256 + threadIdx.x;
    if (idx >= 64 * 64 * 9) return;
    int oc = idx & 63;
    int rest = idx >> 6;
    int k = rest % 9;
    int cin = rest / 9;
    wT[idx] = w[((size_t)oc * 64 + cin) * 9 + k];
}

// w (144,128,KK2) -> wT[(cin*KK2+k)*144 + oc]
__global__ void wtransC_k(const float* __restrict__ w, float* __restrict__ wT,
                          int KK2, int total) {
    int idx = blockIdx.x * 256 + threadIdx.x;
    if (idx >= total) return;
    int oc = idx % 144;
    int rest = idx / 144;
    int k = rest % KK2;
    int cin = rest / KK2;
    wT[idx] = w[((size_t)oc * 128 + cin) * KK2 + k];
}

// ---------------- 2x2 average pool ----------------
__global__ void avgpool_k(const float* __restrict__ x, float* __restrict__ x2) {
    int idx = blockIdx.x * 256 + threadIdx.x;  // < B*T*C*H2*W2 = 2621440
    int w2 = idx & 63;
    int rest = idx >> 6;
    int h2 = rest & 63;
    int p = rest >> 6;  // plane = (b*T+t)*C + c
    const float* src = x + (size_t)p * HW;
    int y = h2 * 2, xx = w2 * 2;
    float v = src[y * WW + xx] + src[y * WW + xx + 1] +
              src[(y + 1) * WW + xx] + src[(y + 1) * WW + xx + 1];
    x2[idx] = 0.25f * v;
}

// ---------------- direct conv, Cin=128 (two 64ch sources), Cout=144 ----------------
// MODE 0: 3x3 pad1 @64x64, srcA=x2[b,i], srcB=x2[b,tc]
// MODE 1: 5x5 pad2 @128x128, srcA=z1[bj], srcB=x[b,tc], fused addend off2u
template <int MODE>
__global__ __launch_bounds__(256) void conv_k(
    const float* __restrict__ x, const float* __restrict__ x2,
    const float* __restrict__ z1, const float* __restrict__ wT,
    const float* __restrict__ bias, const float* __restrict__ addend,
    float* __restrict__ out) {
    constexpr int KS = MODE ? 5 : 3;
    constexpr int PAD = MODE ? 2 : 1;
    constexpr int IM = MODE ? 128 : 64;
    constexpr int KK2 = KS * KS;
    constexpr int ROWS = 16 + KS - 1;
    constexpr int COLS = 32 + KS - 1;
    constexpr int TX = IM / 32;

    const int bj = blockIdx.z;
    const int b = bj >> 2;
    const int j = bj & 3;
    const int i = j + (j >= 2 ? 1 : 0);
    const int ocBase = blockIdx.y * 16;
    const int x0 = (blockIdx.x % TX) * 32;
    const int y0 = (blockIdx.x / TX) * 16;
    const int tid = threadIdx.x;
    const int tx = tid & 15;
    const int ty = tid >> 4;

    const float* srcA;
    const float* srcB;
    if (MODE == 0) {
        srcA = x2 + (size_t)(b * TT + i) * CC * HW2;
        srcB = x2 + (size_t)(b * TT + TCF) * CC * HW2;
    } else {
        srcA = z1 + (size_t)bj * CC * HW;
        srcB = x + (size_t)(b * TT + TCF) * CC * HW;
    }

    __shared__ float sIn[8][ROWS][40];  // row stride 40 floats -> <=2-way bank aliasing

    float acc0[16], acc1[16];
#pragma unroll
    for (int q = 0; q < 16; q++) { acc0[q] = 0.f; acc1[q] = 0.f; }

    for (int cc = 0; cc < 16; ++cc) {
        const int cinBase = cc * 8;
        __syncthreads();
        // stage input tile
        for (int e = tid; e < 8 * ROWS * COLS; e += 256) {
            int c = e / (ROWS * COLS);
            int r = (e / COLS) % ROWS;
            int col = e % COLS;
            int gy = y0 + r - PAD;
            int gx = x0 + col - PAD;
            int cin = cinBase + c;
            const float* sp = (cin < 64) ? (srcA + (size_t)cin * IM * IM)
                                         : (srcB + (size_t)(cin - 64) * IM * IM);
            float v = 0.f;
            if (gy >= 0 && gy < IM && gx >= 0 && gx < IM) v = sp[gy * IM + gx];
            sIn[c][r][col] = v;
        }
        __syncthreads();

        for (int c8 = 0; c8 < 8; ++c8) {
            const float* wrow = wT + ((size_t)(cinBase + c8) * KK2) * 144 + ocBase;
#pragma unroll
            for (int k = 0; k < KK2; ++k) {
                const int kyy = k / KS;
                const int kxx = k % KS;
                float s0 = sIn[c8][ty + kyy][tx + kxx];
                float s1 = sIn[c8][ty + kyy][tx + 16 + kxx];
                const float4* wp4 = (const float4*)(wrow + k * 144);
                float4 wa = wp4[0], wb = wp4[1], wc = wp4[2], wd = wp4[3];
                acc0[0] += wa.x * s0;  acc1[0] += wa.x * s1;
                acc0[1] += wa.y * s0;  acc1[1] += wa.y * s1;
                acc0[2] += wa.z * s0;  acc1[2] += wa.z * s1;
                acc0[3] += wa.w * s0;  acc1[3] += wa.w * s1;
                acc0[4] += wb.x * s0;  acc1[4] += wb.x * s1;
                acc0[5] += wb.y * s0;  acc1[5] += wb.y * s1;
                acc0[6] += wb.z * s0;  acc1[6] += wb.z * s1;
                acc0[7] += wb.w * s0;  acc1[7] += wb.w * s1;
                acc0[8] += wc.x * s0;  acc1[8] += wc.x * s1;
                acc0[9] += wc.y * s0;  acc1[9] += wc.y * s1;
                acc0[10] += wc.z * s0; acc1[10] += wc.z * s1;
                acc0[11] += wc.w * s0; acc1[11] += wc.w * s1;
                acc0[12] += wd.x * s0; acc1[12] += wd.x * s1;
                acc0[13] += wd.y * s0; acc1[13] += wd.y * s1;
                acc0[14] += wd.z * s0; acc1[14] += wd.z * s1;
                acc0[15] += wd.w * s0; acc1[15] += wd.w * s1;
            }
        }
    }

    const size_t imgBase = (size_t)bj * OFFC * IM * IM;
    const int yy = y0 + ty;
#pragma unroll
    for (int oc = 0; oc < 16; oc++) {
        float bsv = bias[ocBase + oc];
        size_t o0 = imgBase + (size_t)(ocBase + oc) * IM * IM + yy * IM + x0 + tx;
        float v0 = acc0[oc] + bsv;
        float v1 = acc1[oc] + bsv;
        if (MODE == 1) {
            v0 += addend[o0];
            v1 += addend[o0 + 16];
        }
        out[o0] = v0;
        out[o0 + 16] = v1;
    }
}

// ---------------- bilinear 2x upsample * 2.0 (JAX half-pixel semantics) ----------------
__global__ void upsample_k(const float* __restrict__ off2, float* __restrict__ off2u) {
    int idx = blockIdx.x * 256 + threadIdx.x;  // < BJ*144*128*128 = 18874368
    int ox = idx & 127;
    int oy = (idx >> 7) & 127;
    int p = idx >> 14;  // bj*144 + ch
    const float* sp = off2 + (size_t)p * HW2;
    float sy = 0.5f * oy - 0.25f;
    float sx = 0.5f * ox - 0.25f;
    float y0f = floorf(sy), x0f = floorf(sx);
    int y0 = (int)y0f, x0 = (int)x0f;
    float fy = sy - y0f, fx = sx - x0f;
    int y0c = max(y0, 0), y1c = min(y0 + 1, 63);
    int x0c = max(x0, 0), x1c = min(x0 + 1, 63);
    float v00 = sp[y0c * 64 + x0c], v01 = sp[y0c * 64 + x1c];
    float v10 = sp[y1c * 64 + x0c], v11 = sp[y1c * 64 + x1c];
    float v = v00 * (1.f - fy) * (1.f - fx) + v01 * (1.f - fy) * fx +
              v10 * fy * (1.f - fx) + v11 * fy * fx;
    off2u[idx] = 2.0f * v;
}

// ---------------- deformable conv (3x3, G=8 offset groups) ----------------
// one block (64 threads) per 16-px row segment of one (b,frame) image
__global__ __launch_bounds__(64) void dconv_k(
    const float* __restrict__ x,    // (B,T,C,H,W)
    const float* __restrict__ off,  // (BJ,144,H,W)
    const float* __restrict__ wT,   // [(cin*9+k)][64 oc]
    float* __restrict__ out, int outMode) {
    const int bj = blockIdx.y;
    const int b = bj >> 2;
    const int j = bj & 3;
    const int i = j + (j >= 2 ? 1 : 0);
    const int seg = blockIdx.x;  // 0..1023
    const int y = seg >> 3;
    const int x0 = (seg & 7) << 4;
    const int tid = threadIdx.x;

    __shared__ float sS[576 * 16];  // [ck = cin*9+k][px]

    const float* xin = x + (size_t)(b * TT + i) * CC * HW;
    const float* offp = off + (size_t)bj * OFFC * HW + y * WW + x0;

    // ---- phase A: bilinear sampling into LDS ----
    const int px = tid & 15;
    const int cinLo = tid >> 4;  // 0..3
    for (int rep = 0; rep < 16; ++rep) {
        const int cin = cinLo + rep * 4;
        const int g = cin >> 3;  // wave-uniform
        const float* xp = xin + (size_t)cin * HW;
#pragma unroll
        for (int k = 0; k < 9; ++k) {
            float dy = offp[(size_t)((g * 9 + k) * 2) * HW + px];
            float dx = offp[(size_t)((g * 9 + k) * 2 + 1) * HW + px];
            const int kyy = k / 3 - 1;
            const int kxx = k % 3 - 1;
            float sy = (float)(y + kyy) + dy;
            float sx = (float)(x0 + px + kxx) + dx;
            float y0f = floorf(sy), x0f = floorf(sx);
            int iy = (int)y0f, ix = (int)x0f;
            float wy = sy - y0f, wx = sx - x0f;
            bool yv0 = (iy >= 0) & (iy < HH);
            bool yv1 = (iy + 1 >= 0) & (iy + 1 < HH);
            bool xv0 = (ix >= 0) & (ix < WW);
            bool xv1 = (ix + 1 >= 0) & (ix + 1 < WW);
            float v00 = (yv0 && xv0) ? xp[iy * WW + ix] : 0.f;
            float v01 = (yv0 && xv1) ? xp[iy * WW + ix + 1] : 0.f;
            float v10 = (yv1 && xv0) ? xp[(iy + 1) * WW + ix] : 0.f;
            float v11 = (yv1 && xv1) ? xp[(iy + 1) * WW + ix + 1] : 0.f;
            float v = v00 * (1.f - wy) * (1.f - wx) + v01 * (1.f - wy) * wx +
                      v10 * wy * (1.f - wx) + v11 * wy * wx;
            sS[(cin * 9 + k) * 16 + px] = v;
        }
    }
    __syncthreads();

    // ---- phase B: 64oc x 16px x 576 dot ----
    const int oc4 = (tid & 15) * 4;
    const int pg = tid >> 4;  // 0..3
    float4 a0 = {0, 0, 0, 0}, a1 = {0, 0, 0, 0}, a2 = {0, 0, 0, 0}, a3 = {0, 0, 0, 0};
#pragma unroll 8
    for (int ck = 0; ck < 576; ++ck) {
        float4 wv = *(const float4*)&wT[ck * 64 + oc4];
        float4 sv = *(const float4*)&sS[ck * 16 + pg * 4];
        a0.x += wv.x * sv.x; a0.y += wv.x * sv.y; a0.z += wv.x * sv.z; a0.w += wv.x * sv.w;
        a1.x += wv.y * sv.x; a1.y += wv.y * sv.y; a1.z += wv.y * sv.z; a1.w += wv.y * sv.w;
        a2.x += wv.z * sv.x; a2.y += wv.z * sv.y; a2.z += wv.z * sv.z; a2.w += wv.z * sv.w;
        a3.x += wv.w * sv.x; a3.y += wv.w * sv.y; a3.z += wv.w * sv.z; a3.w += wv.w * sv.w;
    }

    size_t planeBase;
    if (outMode == 0) planeBase = (size_t)bj * CC * HW;
    else planeBase = (size_t)(b * TT + i) * CC * HW;
    size_t base = planeBase + y * WW + x0 + pg * 4;
    *(float4*)&out[base + (size_t)(oc4 + 0) * HW] = a0;
    *(float4*)&out[base + (size_t)(oc4 + 1) * HW] = a1;
    *(float4*)&out[base + (size_t)(oc4 + 2) * HW] = a2;
    *(float4*)&out[base + (size_t)(oc4 + 3) * HW] = a3;
}

// ---------------- center frame passthrough ----------------
__global__ void copy_center_k(const float* __restrict__ x, float* __restrict__ out) {
    int idx = blockIdx.x * 256 + threadIdx.x;  // < 524288 float4s
    int b = idx >> 18;
    int rem = idx & 262143;
    size_t o = (((size_t)(b * TT + TCF) * CC * HW) >> 2) + rem;
    ((float4*)out)[o] = ((const float4*)x)[o];
}

extern "C" void kernel_launch(void* const* d_in, const int* in_sizes, int n_in,
                              void* d_out, int out_size, void* d_ws, size_t ws_size,
                              hipStream_t stream) {
    const float* x = (const float*)d_in[0];
    const float* w_off1 = (const float*)d_in[1];
    const float* b_off1 = (const float*)d_in[2];
    const float* w_off2 = (const float*)d_in[3];
    const float* b_off2 = (const float*)d_in[4];
    const float* w_align1 = (const float*)d_in[5];
    const float* w_alignf = (const float*)d_in[6];
    float* out = (float*)d_out;
    float* ws = (float*)d_ws;

    float* x2 = ws;                    // 2,621,440
    float* off2 = ws + 2621440;        // 4,718,592
    float* off2u = ws + 7340032;       // 18,874,368
    float* z1 = ws + 26214400;         // 8,388,608
    float* off1 = ws + 34603008;       // 18,874,368
    float* wT1 = ws + 53477376;        // 36,864
    float* wTf = ws + 53514240;        // 36,864
    float* w2T = ws + 53551104;        // 165,888
    float* w1T = ws + 53716992;        // 460,800

    wtransD_k<<<144, 256, 0, stream>>>(w_align1, wT1);
    wtransD_k<<<144, 256, 0, stream>>>(w_alignf, wTf);
    wtransC_k<<<648, 256, 0, stream>>>(w_off2, w2T, 9, 165888);
    wtransC_k<<<1800, 256, 0, stream>>>(w_off1, w1T, 25, 460800);

    avgpool_k<<<10240, 256, 0, stream>>>(x, x2);

    conv_k<0><<<dim3(8, 9, 8), 256, 0, stream>>>(x, x2, nullptr, w2T, b_off2,
                                                 nullptr, off2);
    upsample_k<<<73728, 256, 0, stream>>>(off2, off2u);
    dconv_k<<<dim3(1024, 8), 64, 0, stream>>>(x, off2u, wT1, z1, 0);
    conv_k<1><<<dim3(32, 9, 8), 256, 0, stream>>>(x, nullptr, z1, w1T, b_off1,
                                                  off2u, off1);
    dconv_k<<<dim3(1024, 8), 64, 0, stream>>>(x, off1, wTf, out, 1);
    copy_center_k<<<2048, 256, 0, stream>>>(x, out);
}

// Round 2
// 1267.599 us; speedup vs baseline: 2.5322x; 2.5322x over previous
//
#include <hip/hip_runtime.h>
#include <cstdint>

// Problem constants
#define BB 2
#define TT 5
#define CC 64
#define HH 128
#define WW 128
#define GG 8
#define KKD 9
#define OFFC 144
#define H2 64
#define W2 64
#define TCF 2
#define HW (HH*WW)
#define HW2 (H2*W2)

typedef __attribute__((ext_vector_type(8))) short short8;
typedef __attribute__((ext_vector_type(16))) float floatx16;

static __device__ __forceinline__ unsigned short f2bf(float f) {
    unsigned int u = __float_as_uint(f);
    unsigned int r = (u + 0x7fffu + ((u >> 16) & 1u)) >> 16;
    return (unsigned short)r;
}
static __device__ __forceinline__ float bf2f(unsigned short s) {
    return __uint_as_float(((unsigned int)s) << 16);
}

// ---------------- dconv weight transpose: w (64,64,3,3) -> wT[(cin*9+k)*64 + oc] (fp32)
__global__ void wtransD_k(const float* __restrict__ w, float* __restrict__ wT) {
    int idx = blockIdx.x * 256 + threadIdx.x;
    if (idx >= 64 * 64 * 9) return;
    int oc = idx & 63;
    int rest = idx >> 6;
    int k = rest % 9;
    int cin = rest / 9;
    wT[idx] = w[((size_t)oc * 64 + cin) * 9 + k];
}

// ---------------- conv weight swizzle into MFMA B-fragment order (bf16) ----------------
// layout: [chunk(8)][tap(TAPS)][ocF(5)][lane(64)][j(8)]
// value = W[oc = ocF*32 + (lane&31)][cin = chunk*16 + (lane>>5)*8 + j][tap], 0 if oc>=144
template <int TAPS>
__global__ void wswz_k(const float* __restrict__ w, short* __restrict__ ws) {
    int idx = blockIdx.x * 256 + threadIdx.x;
    if (idx >= 8 * TAPS * 5 * 512) return;
    int jj = idx & 7;
    int lane = (idx >> 3) & 63;
    int rest = idx >> 9;
    int ocF = rest % 5;
    int ct = rest / 5;
    int tap = ct % TAPS;
    int chunk = ct / TAPS;
    int oc = ocF * 32 + (lane & 31);
    int cin = chunk * 16 + (lane >> 5) * 8 + jj;
    float v = 0.f;
    if (oc < OFFC) v = w[((size_t)oc * 128 + cin) * TAPS + tap];
    ws[idx] = (short)f2bf(v);
}

// ---------------- 2x2 average pool ----------------
__global__ void avgpool_k(const float* __restrict__ x, float* __restrict__ x2) {
    int idx = blockIdx.x * 256 + threadIdx.x;  // < 2621440
    int w2 = idx & 63;
    int rest = idx >> 6;
    int h2 = rest & 63;
    int p = rest >> 6;
    const float* src = x + (size_t)p * HW;
    int y = h2 * 2, xx = w2 * 2;
    float v = src[y * WW + xx] + src[y * WW + xx + 1] +
              src[(y + 1) * WW + xx] + src[(y + 1) * WW + xx + 1];
    x2[idx] = 0.25f * v;
}

// ---------------- MFMA conv, Cin=128 (two 64ch sources), Cout=144 (padded 160) --------
// MODE 0: 3x3 pad1 @64x64, srcA=x2[b,i], srcB=x2[b,tc]
// MODE 1: 5x5 pad2 @128x128, srcA=z1[bj], srcB=x[b,tc], fused addend off2u
// Block: 256 thr = 4 waves; block px tile = 256 (OROWS rows x IM cols); oc = all 160.
// Per-tap GEMM: out[px][oc] += In_shifted[px][cin] * W_tap[cin][oc], K-chunks of 16 cin.
template <int MODE>
__global__ __launch_bounds__(256) void convmf_k(
    const float* __restrict__ x, const float* __restrict__ x2,
    const float* __restrict__ z1, const short* __restrict__ wswz,
    const float* __restrict__ bias, const float* __restrict__ addend,
    float* __restrict__ out) {
    constexpr int KS = MODE ? 5 : 3;
    constexpr int PAD = MODE ? 2 : 1;
    constexpr int IM = MODE ? 128 : 64;
    constexpr int TAPS = KS * KS;
    constexpr int OROWS = MODE ? 2 : 4;
    constexpr int SROWS = OROWS + KS - 1;  // 6
    constexpr int SCOLS = IM + KS - 1;     // 132 / 66
    constexpr int CP = 24;                 // 16 cin + 8 pad (48B row stride, 16B aligned)
    constexpr int STG_BYTES = SROWS * SCOLS * CP * 2;
    constexpr int EPI_BYTES = 256 * 33 * 4;
    constexpr int SMEM = STG_BYTES > EPI_BYTES ? STG_BYTES : EPI_BYTES;

    __shared__ char smem[SMEM];
    short* stg = (short*)smem;
    float* epi = (float*)smem;

    const int bj = blockIdx.z;
    const int b = bj >> 2;
    const int j = bj & 3;
    const int i = j + (j >= 2 ? 1 : 0);
    const int y0 = blockIdx.x * OROWS;
    const int tid = threadIdx.x;
    const int w = tid >> 6;
    const int lane = tid & 63;
    const int l31 = lane & 31;
    const int quad = lane >> 5;

    const int wrow = MODE ? (w >> 1) : w;
    const int wcol0 = MODE ? ((w & 1) * 64) : 0;

    const float* srcA;
    const float* srcB;
    if (MODE == 0) {
        srcA = x2 + (size_t)(b * TT + i) * CC * HW2;
        srcB = x2 + (size_t)(b * TT + TCF) * CC * HW2;
    } else {
        srcA = z1 + (size_t)bj * CC * HW;
        srcB = x + (size_t)(b * TT + TCF) * CC * HW;
    }

    floatx16 acc[2][5];
#pragma unroll
    for (int p = 0; p < 2; ++p)
#pragma unroll
        for (int o = 0; o < 5; ++o)
#pragma unroll
            for (int g = 0; g < 16; ++g) acc[p][o][g] = 0.f;

    for (int chunk = 0; chunk < 8; ++chunk) {
        __syncthreads();
        // stage input tile [row][col][cin16] as bf16
        for (int e = tid; e < SROWS * SCOLS * 16; e += 256) {
            int cin = e / (SROWS * SCOLS);
            int rem = e - cin * (SROWS * SCOLS);
            int row = rem / SCOLS;
            int col = rem - row * SCOLS;
            int gy = y0 + row - PAD;
            int gx = col - PAD;
            int cing = chunk * 16 + cin;
            const float* pl = (cing < 64) ? srcA + (size_t)cing * (IM * IM)
                                          : srcB + (size_t)(cing - 64) * (IM * IM);
            float v = 0.f;
            if (gy >= 0 && gy < IM && gx >= 0 && gx < IM) v = pl[gy * IM + gx];
            stg[(row * SCOLS + col) * CP + cin] = (short)f2bf(v);
        }
        __syncthreads();

        for (int tap = 0; tap < TAPS; ++tap) {
            int ky = tap / KS, kx = tap - ky * KS;
            const short* wp = wswz + ((size_t)(chunk * TAPS + tap) * 5 * 64 + lane) * 8;
            short8 bf[5];
#pragma unroll
            for (int o = 0; o < 5; ++o) bf[o] = *(const short8*)(wp + o * 512);
            short8 af[2];
#pragma unroll
            for (int p = 0; p < 2; ++p) {
                int col = wcol0 + p * 32 + l31 + kx;
                af[p] = *(const short8*)&stg[((wrow + ky) * SCOLS + col) * CP + quad * 8];
            }
#pragma unroll
            for (int p = 0; p < 2; ++p)
#pragma unroll
                for (int o = 0; o < 5; ++o)
                    acc[p][o] = __builtin_amdgcn_mfma_f32_32x32x16_bf16(
                        af[p], bf[o], acc[p][o], 0, 0, 0);
        }
    }

    // ---- epilogue: transpose C through LDS for coalesced stores ----
    const size_t imgBase = (size_t)bj * OFFC * (IM * IM);
    const int rr = tid / IM;
    const int xx = tid - rr * IM;
    for (int o = 0; o < 5; ++o) {
        __syncthreads();
#pragma unroll
        for (int p = 0; p < 2; ++p) {
#pragma unroll
            for (int g = 0; g < 16; ++g) {
                int m = (g & 3) + 8 * (g >> 2) + 4 * quad;
                int px = wrow * IM + wcol0 + p * 32 + m;
                epi[px * 33 + l31] = acc[p][o][g];
            }
        }
        __syncthreads();
        for (int ol = 0; ol < 32; ++ol) {
            int oc = o * 32 + ol;
            if (oc >= OFFC) break;
            float v = epi[tid * 33 + ol] + bias[oc];
            size_t ofs = imgBase + (size_t)oc * (IM * IM) + (size_t)(y0 + rr) * IM + xx;
            if (MODE == 1) v += addend[ofs];
            out[ofs] = v;
        }
    }
}

// ---------------- bilinear 2x upsample * 2.0 (JAX half-pixel semantics) ----------------
__global__ void upsample_k(const float* __restrict__ off2, float* __restrict__ off2u) {
    int idx = blockIdx.x * 256 + threadIdx.x;  // < 18874368
    int ox = idx & 127;
    int oy = (idx >> 7) & 127;
    int p = idx >> 14;
    const float* sp = off2 + (size_t)p * HW2;
    float sy = 0.5f * oy - 0.25f;
    float sx = 0.5f * ox - 0.25f;
    float y0f = floorf(sy), x0f = floorf(sx);
    int y0 = (int)y0f, x0 = (int)x0f;
    float fy = sy - y0f, fx = sx - x0f;
    int y0c = max(y0, 0), y1c = min(y0 + 1, 63);
    int x0c = max(x0, 0), x1c = min(x0 + 1, 63);
    float v00 = sp[y0c * 64 + x0c], v01 = sp[y0c * 64 + x1c];
    float v10 = sp[y1c * 64 + x0c], v11 = sp[y1c * 64 + x1c];
    float v = v00 * (1.f - fy) * (1.f - fx) + v01 * (1.f - fy) * fx +
              v10 * fy * (1.f - fx) + v11 * fy * fx;
    off2u[idx] = 2.0f * v;
}

// ---------------- deformable conv (3x3, G=8 offset groups) ----------------
// one block (64 threads) per 16-px row segment; samples cached bf16 in LDS
__global__ __launch_bounds__(64) void dconv_k(
    const float* __restrict__ x,    // (B,T,C,H,W)
    const float* __restrict__ off,  // (BJ,144,H,W)
    const float* __restrict__ wT,   // [(cin*9+k)][64 oc] fp32
    float* __restrict__ out, int outMode) {
    const int bj = blockIdx.y;
    const int b = bj >> 2;
    const int j = bj & 3;
    const int i = j + (j >= 2 ? 1 : 0);
    const int seg = blockIdx.x;  // 0..1023
    const int y = seg >> 3;
    const int x0 = (seg & 7) << 4;
    const int tid = threadIdx.x;

    __shared__ short sS[576 * 16];  // bf16 samples [ck][px] -> 18.4 KB, 8 blocks/CU

    const float* xin = x + (size_t)(b * TT + i) * CC * HW;
    const float* offp = off + (size_t)bj * OFFC * HW + y * WW + x0;

    // ---- phase A: bilinear sampling into LDS ----
    const int px = tid & 15;
    const int cinLo = tid >> 4;  // 0..3
    for (int rep = 0; rep < 16; ++rep) {
        const int cin = cinLo + rep * 4;
        const int g = cin >> 3;
        const float* xp = xin + (size_t)cin * HW;
#pragma unroll
        for (int k = 0; k < 9; ++k) {
            float dy = offp[(size_t)((g * 9 + k) * 2) * HW + px];
            float dx = offp[(size_t)((g * 9 + k) * 2 + 1) * HW + px];
            const int kyy = k / 3 - 1;
            const int kxx = k % 3 - 1;
            float sy = (float)(y + kyy) + dy;
            float sx = (float)(x0 + px + kxx) + dx;
            float y0f = floorf(sy), x0f = floorf(sx);
            int iy = (int)y0f, ix = (int)x0f;
            float wy = sy - y0f, wx = sx - x0f;
            bool yv0 = (iy >= 0) & (iy < HH);
            bool yv1 = (iy + 1 >= 0) & (iy + 1 < HH);
            bool xv0 = (ix >= 0) & (ix < WW);
            bool xv1 = (ix + 1 >= 0) & (ix + 1 < WW);
            float v00 = (yv0 && xv0) ? xp[iy * WW + ix] : 0.f;
            float v01 = (yv0 && xv1) ? xp[iy * WW + ix + 1] : 0.f;
            float v10 = (yv1 && xv0) ? xp[(iy + 1) * WW + ix] : 0.f;
            float v11 = (yv1 && xv1) ? xp[(iy + 1) * WW + ix + 1] : 0.f;
            float v = v00 * (1.f - wy) * (1.f - wx) + v01 * (1.f - wy) * wx +
                      v10 * wy * (1.f - wx) + v11 * wy * wx;
            sS[(cin * 9 + k) * 16 + px] = (short)f2bf(v);
        }
    }
    __syncthreads();

    // ---- phase B: 64oc x 16px x 576 dot ----
    const int oc4 = (tid & 15) * 4;
    const int pg = tid >> 4;  // 0..3
    float4 a0 = {0, 0, 0, 0}, a1 = {0, 0, 0, 0}, a2 = {0, 0, 0, 0}, a3 = {0, 0, 0, 0};
#pragma unroll 8
    for (int ck = 0; ck < 576; ++ck) {
        float4 wv = *(const float4*)&wT[ck * 64 + oc4];
        ushort4 su = *(const ushort4*)&sS[ck * 16 + pg * 4];
        float s0 = bf2f(su.x), s1 = bf2f(su.y), s2 = bf2f(su.z), s3 = bf2f(su.w);
        a0.x += wv.x * s0; a0.y += wv.x * s1; a0.z += wv.x * s2; a0.w += wv.x * s3;
        a1.x += wv.y * s0; a1.y += wv.y * s1; a1.z += wv.y * s2; a1.w += wv.y * s3;
        a2.x += wv.z * s0; a2.y += wv.z * s1; a2.z += wv.z * s2; a2.w += wv.z * s3;
        a3.x += wv.w * s0; a3.y += wv.w * s1; a3.z += wv.w * s2; a3.w += wv.w * s3;
    }

    size_t planeBase;
    if (outMode == 0) planeBase = (size_t)bj * CC * HW;
    else planeBase = (size_t)(b * TT + i) * CC * HW;
    size_t base = planeBase + y * WW + x0 + pg * 4;
    *(float4*)&out[base + (size_t)(oc4 + 0) * HW] = a0;
    *(float4*)&out[base + (size_t)(oc4 + 1) * HW] = a1;
    *(float4*)&out[base + (size_t)(oc4 + 2) * HW] = a2;
    *(float4*)&out[base + (size_t)(oc4 + 3) * HW] = a3;
}

// ---------------- center frame passthrough ----------------
__global__ void copy_center_k(const float* __restrict__ x, float* __restrict__ out) {
    int idx = blockIdx.x * 256 + threadIdx.x;  // < 524288 float4s
    int b = idx >> 18;
    int rem = idx & 262143;
    size_t o = (((size_t)(b * TT + TCF) * CC * HW) >> 2) + rem;
    ((float4*)out)[o] = ((const float4*)x)[o];
}

extern "C" void kernel_launch(void* const* d_in, const int* in_sizes, int n_in,
                              void* d_out, int out_size, void* d_ws, size_t ws_size,
                              hipStream_t stream) {
    const float* x = (const float*)d_in[0];
    const float* w_off1 = (const float*)d_in[1];
    const float* b_off1 = (const float*)d_in[2];
    const float* w_off2 = (const float*)d_in[3];
    const float* b_off2 = (const float*)d_in[4];
    const float* w_align1 = (const float*)d_in[5];
    const float* w_alignf = (const float*)d_in[6];
    float* out = (float*)d_out;
    float* ws = (float*)d_ws;

    float* x2 = ws;                     // 2,621,440
    float* off2 = ws + 2621440;         // 4,718,592
    float* off2u = ws + 7340032;        // 18,874,368
    float* z1 = ws + 26214400;          // 8,388,608
    float* off1 = ws + 34603008;        // 18,874,368
    float* wT1 = ws + 53477376;         // 36,864
    float* wTf = ws + 53514240;         // 36,864
    short* w2s = (short*)(ws + 53551104);  // 184,320 shorts (92,160 float slots)
    short* w1s = (short*)(ws + 53643264);  // 512,000 shorts (256,000 float slots)

    wtransD_k<<<144, 256, 0, stream>>>(w_align1, wT1);
    wtransD_k<<<144, 256, 0, stream>>>(w_alignf, wTf);
    wswz_k<9><<<720, 256, 0, stream>>>(w_off2, w2s);
    wswz_k<25><<<2000, 256, 0, stream>>>(w_off1, w1s);

    avgpool_k<<<10240, 256, 0, stream>>>(x, x2);

    convmf_k<0><<<dim3(16, 1, 8), 256, 0, stream>>>(x, x2, nullptr, w2s, b_off2,
                                                    nullptr, off2);
    upsample_k<<<73728, 256, 0, stream>>>(off2, off2u);
    dconv_k<<<dim3(1024, 8), 64, 0, stream>>>(x, off2u, wT1, z1, 0);
    convmf_k<1><<<dim3(64, 1, 8), 256, 0, stream>>>(x, nullptr, z1, w1s, b_off1,
                                                    off2u, off1);
    dconv_k<<<dim3(1024, 8), 64, 0, stream>>>(x, off1, wTf, out, 1);
    copy_center_k<<<2048, 256, 0, stream>>>(x, out);
}

// Round 3
// 863.549 us; speedup vs baseline: 3.7170x; 1.4679x over previous
//
#include <hip/hip_runtime.h>
#include <cstdint>

// Problem constants
#define BB 2
#define TT 5
#define CC 64
#define HH 128
#define WW 128
#define GG 8
#define KKD 9
#define OFFC 144
#define H2 64
#define W2 64
#define TCF 2
#define HW (HH*WW)
#define HW2 (H2*W2)

typedef __attribute__((ext_vector_type(8))) short short8;
typedef __attribute__((ext_vector_type(16))) float floatx16;

static __device__ __forceinline__ unsigned short f2bf(float f) {
    unsigned int u = __float_as_uint(f);
    unsigned int r = (u + 0x7fffu + ((u >> 16) & 1u)) >> 16;
    return (unsigned short)r;
}

// ---------------- dconv weight swizzle into MFMA B-fragment order (bf16) -------------
// layout: [chunk(36)][tile(2)][lane(64)][j(8)]
// value = w[oc = tile*32 + (lane&31)][cin = ck/9][kt = ck%9], ck = chunk*16+(lane>>5)*8+j
__global__ void wswzD_k(const float* __restrict__ w, short* __restrict__ ws) {
    int idx = blockIdx.x * 256 + threadIdx.x;
    if (idx >= 36864) return;
    int j = idx & 7;
    int lane = (idx >> 3) & 63;
    int tile = (idx >> 9) & 1;
    int chunk = idx >> 10;
    int ck = chunk * 16 + (lane >> 5) * 8 + j;
    int oc = tile * 32 + (lane & 31);
    int cin = ck / 9;
    int kt = ck - cin * 9;
    ws[idx] = (short)f2bf(w[((size_t)oc * 64 + cin) * 9 + kt]);
}

// ---------------- conv weight swizzle into MFMA B-fragment order (bf16) ----------------
// layout: [chunk(8)][tap(TAPS)][ocF(5)][lane(64)][j(8)]
template <int TAPS>
__global__ void wswz_k(const float* __restrict__ w, short* __restrict__ ws) {
    int idx = blockIdx.x * 256 + threadIdx.x;
    if (idx >= 8 * TAPS * 5 * 512) return;
    int jj = idx & 7;
    int lane = (idx >> 3) & 63;
    int rest = idx >> 9;
    int ocF = rest % 5;
    int ct = rest / 5;
    int tap = ct % TAPS;
    int chunk = ct / TAPS;
    int oc = ocF * 32 + (lane & 31);
    int cin = chunk * 16 + (lane >> 5) * 8 + jj;
    float v = 0.f;
    if (oc < OFFC) v = w[((size_t)oc * 128 + cin) * TAPS + tap];
    ws[idx] = (short)f2bf(v);
}

// ---------------- 2x2 average pool ----------------
__global__ void avgpool_k(const float* __restrict__ x, float* __restrict__ x2) {
    int idx = blockIdx.x * 256 + threadIdx.x;  // < 2621440
    int w2 = idx & 63;
    int rest = idx >> 6;
    int h2 = rest & 63;
    int p = rest >> 6;
    const float* src = x + (size_t)p * HW;
    int y = h2 * 2, xx = w2 * 2;
    float v = src[y * WW + xx] + src[y * WW + xx + 1] +
              src[(y + 1) * WW + xx] + src[(y + 1) * WW + xx + 1];
    x2[idx] = 0.25f * v;
}

// ---------------- MFMA conv, Cin=128 (two 64ch sources), Cout=144 (padded 160) --------
template <int MODE>
__global__ __launch_bounds__(256) void convmf_k(
    const float* __restrict__ x, const float* __restrict__ x2,
    const float* __restrict__ z1, const short* __restrict__ wswz,
    const float* __restrict__ bias, const float* __restrict__ addend,
    float* __restrict__ out) {
    constexpr int KS = MODE ? 5 : 3;
    constexpr int PAD = MODE ? 2 : 1;
    constexpr int IM = MODE ? 128 : 64;
    constexpr int TAPS = KS * KS;
    constexpr int OROWS = MODE ? 2 : 4;
    constexpr int SROWS = OROWS + KS - 1;
    constexpr int SCOLS = IM + KS - 1;
    constexpr int CP = 24;
    constexpr int STG_BYTES = SROWS * SCOLS * CP * 2;
    constexpr int EPI_BYTES = 256 * 33 * 4;
    constexpr int SMEM = STG_BYTES > EPI_BYTES ? STG_BYTES : EPI_BYTES;

    __shared__ char smem[SMEM];
    short* stg = (short*)smem;
    float* epi = (float*)smem;

    const int bj = blockIdx.z;
    const int b = bj >> 2;
    const int j = bj & 3;
    const int i = j + (j >= 2 ? 1 : 0);
    const int y0 = blockIdx.x * OROWS;
    const int tid = threadIdx.x;
    const int w = tid >> 6;
    const int lane = tid & 63;
    const int l31 = lane & 31;
    const int quad = lane >> 5;

    const int wrow = MODE ? (w >> 1) : w;
    const int wcol0 = MODE ? ((w & 1) * 64) : 0;

    const float* srcA;
    const float* srcB;
    if (MODE == 0) {
        srcA = x2 + (size_t)(b * TT + i) * CC * HW2;
        srcB = x2 + (size_t)(b * TT + TCF) * CC * HW2;
    } else {
        srcA = z1 + (size_t)bj * CC * HW;
        srcB = x + (size_t)(b * TT + TCF) * CC * HW;
    }

    floatx16 acc[2][5];
#pragma unroll
    for (int p = 0; p < 2; ++p)
#pragma unroll
        for (int o = 0; o < 5; ++o)
#pragma unroll
            for (int g = 0; g < 16; ++g) acc[p][o][g] = 0.f;

    for (int chunk = 0; chunk < 8; ++chunk) {
        __syncthreads();
        for (int e = tid; e < SROWS * SCOLS * 16; e += 256) {
            int cin = e / (SROWS * SCOLS);
            int rem = e - cin * (SROWS * SCOLS);
            int row = rem / SCOLS;
            int col = rem - row * SCOLS;
            int gy = y0 + row - PAD;
            int gx = col - PAD;
            int cing = chunk * 16 + cin;
            const float* pl = (cing < 64) ? srcA + (size_t)cing * (IM * IM)
                                          : srcB + (size_t)(cing - 64) * (IM * IM);
            float v = 0.f;
            if (gy >= 0 && gy < IM && gx >= 0 && gx < IM) v = pl[gy * IM + gx];
            stg[(row * SCOLS + col) * CP + cin] = (short)f2bf(v);
        }
        __syncthreads();

        for (int tap = 0; tap < TAPS; ++tap) {
            int ky = tap / KS, kx = tap - ky * KS;
            const short* wp = wswz + ((size_t)(chunk * TAPS + tap) * 5 * 64 + lane) * 8;
            short8 bf[5];
#pragma unroll
            for (int o = 0; o < 5; ++o) bf[o] = *(const short8*)(wp + o * 512);
            short8 af[2];
#pragma unroll
            for (int p = 0; p < 2; ++p) {
                int col = wcol0 + p * 32 + l31 + kx;
                af[p] = *(const short8*)&stg[((wrow + ky) * SCOLS + col) * CP + quad * 8];
            }
#pragma unroll
            for (int p = 0; p < 2; ++p)
#pragma unroll
                for (int o = 0; o < 5; ++o)
                    acc[p][o] = __builtin_amdgcn_mfma_f32_32x32x16_bf16(
                        af[p], bf[o], acc[p][o], 0, 0, 0);
        }
    }

    const size_t imgBase = (size_t)bj * OFFC * (IM * IM);
    const int rr = tid / IM;
    const int xx = tid - rr * IM;
    for (int o = 0; o < 5; ++o) {
        __syncthreads();
#pragma unroll
        for (int p = 0; p < 2; ++p) {
#pragma unroll
            for (int g = 0; g < 16; ++g) {
                int m = (g & 3) + 8 * (g >> 2) + 4 * quad;
                int px = wrow * IM + wcol0 + p * 32 + m;
                epi[px * 33 + l31] = acc[p][o][g];
            }
        }
        __syncthreads();
        for (int ol = 0; ol < 32; ++ol) {
            int oc = o * 32 + ol;
            if (oc >= OFFC) break;
            float v = epi[tid * 33 + ol] + bias[oc];
            size_t ofs = imgBase + (size_t)oc * (IM * IM) + (size_t)(y0 + rr) * IM + xx;
            if (MODE == 1) v += addend[ofs];
            out[ofs] = v;
        }
    }
}

// ---------------- bilinear 2x upsample * 2.0 ----------------
__global__ void upsample_k(const float* __restrict__ off2, float* __restrict__ off2u) {
    int idx = blockIdx.x * 256 + threadIdx.x;  // < 18874368
    int ox = idx & 127;
    int oy = (idx >> 7) & 127;
    int p = idx >> 14;
    const float* sp = off2 + (size_t)p * HW2;
    float sy = 0.5f * oy - 0.25f;
    float sx = 0.5f * ox - 0.25f;
    float y0f = floorf(sy), x0f = floorf(sx);
    int y0 = (int)y0f, x0 = (int)x0f;
    float fy = sy - y0f, fx = sx - x0f;
    int y0c = max(y0, 0), y1c = min(y0 + 1, 63);
    int x0c = max(x0, 0), x1c = min(x0 + 1, 63);
    float v00 = sp[y0c * 64 + x0c], v01 = sp[y0c * 64 + x1c];
    float v10 = sp[y1c * 64 + x0c], v11 = sp[y1c * 64 + x1c];
    float v = v00 * (1.f - fy) * (1.f - fx) + v01 * (1.f - fy) * fx +
              v10 * fy * (1.f - fx) + v11 * fy * fx;
    off2u[idx] = 2.0f * v;
}

// ---------------- deformable conv (3x3, G=8 offset groups), MFMA phase B -------------
// block = 256 thr (4 waves) per 32-px row segment of one (b,frame) image.
// LDS: sS[px(32)][ck(576)+pad8] bf16 (row 584 shorts = 1168 B, 16B aligned)
#define SROW 584
__global__ __launch_bounds__(256, 4) void dconv_k(
    const float* __restrict__ x,    // (B,T,C,H,W)
    const float* __restrict__ off,  // (BJ,144,H,W)
    const short* __restrict__ wsw,  // swizzled B-frags [chunk36][tile2][lane64][8]
    float* __restrict__ out, int outMode) {
    const int bj = blockIdx.y;
    const int b = bj >> 2;
    const int j = bj & 3;
    const int i = j + (j >= 2 ? 1 : 0);
    const int seg = blockIdx.x;  // 0..511
    const int y = seg >> 2;
    const int x0 = (seg & 3) << 5;
    const int tid = threadIdx.x;

    __shared__ short sS[32 * SROW];  // 37376 B; reused as float Pbuf[4][32][33] later
    float* Pbuf = (float*)sS;

    const float* xin = x + (size_t)(b * TT + i) * CC * HW;
    const float* offp = off + (size_t)bj * OFFC * HW + y * WW + x0;

    // ---- phase A: bilinear sampling into LDS ----
    {
        const int g = tid >> 5;   // 0..7 offset group
        const int px = tid & 31;
        short* srow = sS + px * SROW + g * 72;  // ck base = (g*8)*9
#pragma unroll
        for (int k = 0; k < 9; ++k) {
            float dy = offp[(size_t)((g * 9 + k) * 2) * HW + px];
            float dx = offp[(size_t)((g * 9 + k) * 2 + 1) * HW + px];
            const int kyy = k / 3 - 1;
            const int kxx = k % 3 - 1;
            float sy = (float)(y + kyy) + dy;
            float sx = (float)(x0 + px + kxx) + dx;
            float y0f = floorf(sy), x0f = floorf(sx);
            int iy = (int)y0f, ix = (int)x0f;
            float wy = sy - y0f, wx = sx - x0f;
            bool yv0 = (iy >= 0) & (iy < HH);
            bool yv1 = (iy + 1 >= 0) & (iy + 1 < HH);
            bool xv0 = (ix >= 0) & (ix < WW);
            bool xv1 = (ix + 1 >= 0) & (ix + 1 < WW);
            float w00 = (yv0 && xv0) ? (1.f - wy) * (1.f - wx) : 0.f;
            float w01 = (yv0 && xv1) ? (1.f - wy) * wx : 0.f;
            float w10 = (yv1 && xv0) ? wy * (1.f - wx) : 0.f;
            float w11 = (yv1 && xv1) ? wy * wx : 0.f;
            int iy0 = min(max(iy, 0), HH - 1);
            int iy1 = min(max(iy + 1, 0), HH - 1);
            int ix0 = min(max(ix, 0), WW - 1);
            int ix1 = min(max(ix + 1, 0), WW - 1);
            int o00 = iy0 * WW + ix0, o01 = iy0 * WW + ix1;
            int o10 = iy1 * WW + ix0, o11 = iy1 * WW + ix1;
            const float* xp = xin + (size_t)(g * 8) * HW;
#pragma unroll 4
            for (int c = 0; c < 8; ++c) {
                float v = xp[o00] * w00 + xp[o01] * w01 + xp[o10] * w10 + xp[o11] * w11;
                srow[c * 9 + k] = (short)f2bf(v);
                xp += HW;
            }
        }
    }
    __syncthreads();

    // ---- phase B: C[px 32][oc 64] = S * W, K=576, MFMA 32x32x16 ----
    const int wv = tid >> 6;      // wave 0..3
    const int lane = tid & 63;
    const int tile = wv >> 1;     // oc tile
    const int kw = wv & 1;        // K half
    floatx16 acc;
#pragma unroll
    for (int g = 0; g < 16; ++g) acc[g] = 0.f;

    const short* aBase = sS + (lane & 31) * SROW + (lane >> 5) * 8;
    const short* bBase = wsw + ((size_t)tile * 64 + lane) * 8;
    for (int chunk = kw * 18; chunk < kw * 18 + 18; ++chunk) {
        short8 af = *(const short8*)(aBase + chunk * 16);
        short8 bf = *(const short8*)(bBase + (size_t)chunk * 1024);
        acc = __builtin_amdgcn_mfma_f32_32x32x16_bf16(af, bf, acc, 0, 0, 0);
    }

    __syncthreads();  // all waves done reading sS
    {
        const int n = lane & 31;
#pragma unroll
        for (int g = 0; g < 16; ++g) {
            int m = (g & 3) + 8 * (g >> 2) + 4 * (lane >> 5);
            Pbuf[wv * 1056 + m * 33 + n] = acc[g];
        }
    }
    __syncthreads();

    // ---- epilogue: reduce K-halves, store ----
    size_t planeBase;
    if (outMode == 0) planeBase = (size_t)bj * CC * HW;
    else planeBase = (size_t)(b * TT + i) * CC * HW;
    const size_t rowBase = planeBase + (size_t)y * WW + x0;
#pragma unroll
    for (int rep = 0; rep < 8; ++rep) {
        int elem = rep * 256 + tid;
        int oc = elem >> 5;
        int px = elem & 31;
        int t = oc >> 5;
        int n = oc & 31;
        float v = Pbuf[(t * 2) * 1056 + px * 33 + n] +
                  Pbuf[(t * 2 + 1) * 1056 + px * 33 + n];
        out[rowBase + (size_t)oc * HW + px] = v;
    }
}

// ---------------- center frame passthrough ----------------
__global__ void copy_center_k(const float* __restrict__ x, float* __restrict__ out) {
    int idx = blockIdx.x * 256 + threadIdx.x;  // < 524288 float4s
    int b = idx >> 18;
    int rem = idx & 262143;
    size_t o = (((size_t)(b * TT + TCF) * CC * HW) >> 2) + rem;
    ((float4*)out)[o] = ((const float4*)x)[o];
}

extern "C" void kernel_launch(void* const* d_in, const int* in_sizes, int n_in,
                              void* d_out, int out_size, void* d_ws, size_t ws_size,
                              hipStream_t stream) {
    const float* x = (const float*)d_in[0];
    const float* w_off1 = (const float*)d_in[1];
    const float* b_off1 = (const float*)d_in[2];
    const float* w_off2 = (const float*)d_in[3];
    const float* b_off2 = (const float*)d_in[4];
    const float* w_align1 = (const float*)d_in[5];
    const float* w_alignf = (const float*)d_in[6];
    float* out = (float*)d_out;
    float* ws = (float*)d_ws;

    float* x2 = ws;                     // 2,621,440
    float* off2 = ws + 2621440;         // 4,718,592
    float* off2u = ws + 7340032;        // 18,874,368
    float* z1 = ws + 26214400;          // 8,388,608
    float* off1 = ws + 34603008;        // 18,874,368
    short* wsD1 = (short*)(ws + 53477376);  // 36,864 shorts
    short* wsDf = (short*)(ws + 53514240);  // 36,864 shorts
    short* w2s = (short*)(ws + 53551104);   // 184,320 shorts
    short* w1s = (short*)(ws + 53643264);   // 512,000 shorts

    wswzD_k<<<144, 256, 0, stream>>>(w_align1, wsD1);
    wswzD_k<<<144, 256, 0, stream>>>(w_alignf, wsDf);
    wswz_k<9><<<720, 256, 0, stream>>>(w_off2, w2s);
    wswz_k<25><<<2000, 256, 0, stream>>>(w_off1, w1s);

    avgpool_k<<<10240, 256, 0, stream>>>(x, x2);

    convmf_k<0><<<dim3(16, 1, 8), 256, 0, stream>>>(x, x2, nullptr, w2s, b_off2,
                                                    nullptr, off2);
    upsample_k<<<73728, 256, 0, stream>>>(off2, off2u);
    dconv_k<<<dim3(512, 8), 256, 0, stream>>>(x, off2u, wsD1, z1, 0);
    convmf_k<1><<<dim3(64, 1, 8), 256, 0, stream>>>(x, nullptr, z1, w1s, b_off1,
                                                    off2u, off1);
    dconv_k<<<dim3(512, 8), 256, 0, stream>>>(x, off1, wsDf, out, 1);
    copy_center_k<<<2048, 256, 0, stream>>>(x, out);
}

// Round 4
// 760.022 us; speedup vs baseline: 4.2233x; 1.1362x over previous
//
#include <hip/hip_runtime.h>
#include <cstdint>

// Problem constants
#define BB 2
#define TT 5
#define CC 64
#define HH 128
#define WW 128
#define GG 8
#define KKD 9
#define OFFC 144
#define H2 64
#define W2 64
#define TCF 2
#define HW (HH*WW)
#define HW2 (H2*W2)
#define PLANE1 278784  // 132*132*16 shorts (full-res padded NHWC chunk plane)
#define PLANE0 69696   // 66*66*16 shorts (half-res padded NHWC chunk plane)

typedef __attribute__((ext_vector_type(4))) short short4v;
typedef __attribute__((ext_vector_type(8))) short short8;
typedef __attribute__((ext_vector_type(16))) float floatx16;

static __device__ __forceinline__ unsigned short f2bf(float f) {
    unsigned int u = __float_as_uint(f);
    unsigned int r = (u + 0x7fffu + ((u >> 16) & 1u)) >> 16;
    return (unsigned short)r;
}

typedef __attribute__((address_space(1))) const unsigned int g_u32;
typedef __attribute__((address_space(3))) unsigned int l_u32;
static __device__ __forceinline__ void async16(const short* g, short* l) {
    __builtin_amdgcn_global_load_lds((g_u32*)g, (l_u32*)l, 16, 0, 0);
}

// ---------------- dconv weight swizzle into MFMA B-fragment order (bf16) -------------
// layout: [chunk(36)][tile(2)][lane(64)][j(8)]
__global__ void wswzD_k(const float* __restrict__ w, short* __restrict__ ws) {
    int idx = blockIdx.x * 256 + threadIdx.x;
    if (idx >= 36864) return;
    int j = idx & 7;
    int lane = (idx >> 3) & 63;
    int tile = (idx >> 9) & 1;
    int chunk = idx >> 10;
    int ck = chunk * 16 + (lane >> 5) * 8 + j;
    int oc = tile * 32 + (lane & 31);
    int cin = ck / 9;
    int kt = ck - cin * 9;
    ws[idx] = (short)f2bf(w[((size_t)oc * 64 + cin) * 9 + kt]);
}

// ---------------- conv weight swizzle into MFMA fragment order (bf16) ----------------
// layout: [chunk(8)][tap(TAPS)][ocF(5)][lane(64)][j(8)]
// value = W[oc = ocF*32 + (lane&31)][cin = chunk*16 + (lane>>5)*8 + j][tap]
// (used as MFMA A-operand: m=oc on lane&31, k=cin on upper — same per-lane structure)
template <int TAPS>
__global__ void wswz_k(const float* __restrict__ w, short* __restrict__ ws) {
    int idx = blockIdx.x * 256 + threadIdx.x;
    if (idx >= 8 * TAPS * 5 * 512) return;
    int jj = idx & 7;
    int lane = (idx >> 3) & 63;
    int rest = idx >> 9;
    int ocF = rest % 5;
    int ct = rest / 5;
    int tap = ct % TAPS;
    int chunk = ct / TAPS;
    int oc = ocF * 32 + (lane & 31);
    int cin = chunk * 16 + (lane >> 5) * 8 + jj;
    float v = 0.f;
    if (oc < OFFC) v = w[((size_t)oc * 128 + cin) * TAPS + tap];
    ws[idx] = (short)f2bf(v);
}

// ---------------- 2x2 average pool -> padded NHWC-bf16 chunk planes ----------------
// x2T layout: [img(10)][chunk(4)][row(66)][col(66)][cin(16)] bf16, pad=1 (pre-zeroed)
__global__ void avgpool_k(const float* __restrict__ x, short* __restrict__ x2T) {
    __shared__ float sL[64 * 17];
    const int h2 = blockIdx.x;
    const int chunk = blockIdx.y;
    const int img = blockIdx.z;
    const int tid = threadIdx.x;
    const float* base = x + ((size_t)img * 64 + chunk * 16) * HW + (size_t)(2 * h2) * WW;
#pragma unroll
    for (int it = 0; it < 4; ++it) {
        int e = it * 256 + tid;
        int cin = e >> 6, w2 = e & 63;
        const float* sp = base + (size_t)cin * HW + 2 * w2;
        sL[w2 * 17 + cin] = 0.25f * (sp[0] + sp[1] + sp[WW] + sp[WW + 1]);
    }
    __syncthreads();
    int w2 = tid >> 2, cg = tid & 3;
    short4v sv;
#pragma unroll
    for (int q = 0; q < 4; ++q) sv[q] = (short)f2bf(sL[w2 * 17 + cg * 4 + q]);
    *(short4v*)&x2T[((size_t)img * 4 + chunk) * PLANE0 +
                    ((size_t)(h2 + 1) * 66 + (w2 + 1)) * 16 + cg * 4] = sv;
}

// ---------------- center-frame transpose -> padded NHWC-bf16 chunk planes ------------
// xT layout: [b(2)][chunk(4)][row(132)][col(132)][cin(16)] bf16, pad=2 (pre-zeroed)
__global__ void xtrans_k(const float* __restrict__ x, short* __restrict__ xT) {
    __shared__ float sL[128 * 17];
    const int row = blockIdx.x;
    const int chunk = blockIdx.y;
    const int b = blockIdx.z;
    const int tid = threadIdx.x;
    const float* base = x + ((size_t)(b * 5 + TCF) * 64 + chunk * 16) * HW + (size_t)row * WW;
#pragma unroll
    for (int it = 0; it < 8; ++it) {
        int e = it * 256 + tid;
        int cin = e >> 7, col = e & 127;
        sL[col * 17 + cin] = base[(size_t)cin * HW + col];
    }
    __syncthreads();
    int col = tid >> 1, half = tid & 1;
    short8 sv;
#pragma unroll
    for (int q = 0; q < 8; ++q) sv[q] = (short)f2bf(sL[col * 17 + half * 8 + q]);
    *(short8*)&xT[((size_t)b * 4 + chunk) * PLANE1 +
                  ((size_t)(row + 2) * 132 + (col + 2)) * 16 + half * 8] = sv;
}

// ---------------- MFMA conv from NHWC-bf16 planes, Cout=144 (padded 160) -------------
// MODE 0: 3x3 @64x64 (srcA=x2T[b,i], srcB=x2T[b,tc]); MODE 1: 5x5 @128x128
// (srcA=z1T[bj], srcB=xT[b], fused addend off2u). 512 thr = 8 waves;
// block tile = OROWS rows x IM cols x 160 oc; wave = 1 px-frag x 5 oc-frags.
// A(MFMA)=weights (m=oc), B=pixels (n=px) -> C has px on lane&31: direct stores.
template <int MODE>
__global__ __launch_bounds__(512) void convmf_k(
    const short* __restrict__ srcAT, const short* __restrict__ srcBT,
    const short* __restrict__ wswz, const float* __restrict__ bias,
    const float* __restrict__ addend, float* __restrict__ out) {
    constexpr int KS = MODE ? 5 : 3;
    constexpr int IM = MODE ? 128 : 64;
    constexpr int PD = IM + KS - 1;        // 132 / 66
    constexpr int TAPS = KS * KS;
    constexpr int OROWS = MODE ? 2 : 4;
    constexpr int SROWS = OROWS + KS - 1;  // 6
    constexpr int PLANE = PD * PD * 16;
    constexpr int SLAB16 = SROWS * PD * 2;  // 16B units per slab

    __shared__ __align__(16) short stg[2][SROWS * PD * 16];

    const int bj = blockIdx.z;
    const int b = bj >> 2;
    const int j = bj & 3;
    const int i = j + (j >= 2 ? 1 : 0);
    const int y0 = blockIdx.x * OROWS;
    const int tid = threadIdx.x;
    const int wave = tid >> 6;
    const int lane = tid & 63;
    const int l31 = lane & 31;
    const int quad = lane >> 5;
    const int wr = MODE ? (wave >> 2) : (wave >> 1);
    const int wc0 = MODE ? ((wave & 3) * 32) : ((wave & 1) * 32);

    const short* srcA;
    const short* srcB;
    if (MODE == 0) {
        srcA = srcAT + (size_t)((b * 5 + i) * 4) * PLANE;
        srcB = srcAT + (size_t)((b * 5 + TCF) * 4) * PLANE;
    } else {
        srcA = srcAT + (size_t)(bj * 4) * PLANE;
        srcB = srcBT + (size_t)(b * 4) * PLANE;
    }

    floatx16 acc[5];
#pragma unroll
    for (int o = 0; o < 5; ++o)
#pragma unroll
        for (int g = 0; g < 16; ++g) acc[o][g] = 0.f;

    auto stage = [&](int c, int sIdx) {
        const short* plane = (c < 4) ? (srcA + (size_t)c * PLANE)
                                     : (srcB + (size_t)(c - 4) * PLANE);
        const short* srcRow = plane + (size_t)y0 * (PD * 16);
        short* dst = stg[sIdx];
        for (int base = wave * 64; base < SLAB16; base += 512) {
            int b2 = min(base, SLAB16 - 64);
            async16(srcRow + (size_t)(b2 + lane) * 8, dst + (size_t)b2 * 8);
        }
    };

    stage(0, 0);
    for (int c = 0; c < 8; ++c) {
        __syncthreads();
        if (c < 7) stage(c + 1, (c + 1) & 1);
        const short* sbuf = stg[c & 1];
        const short* wpc = wswz + (size_t)c * TAPS * 2560 + lane * 8;
#pragma unroll 5
        for (int tap = 0; tap < TAPS; ++tap) {
            const int ky = tap / KS, kx = tap - ky * KS;
            short8 wf[5];
            const short* wp = wpc + (size_t)tap * 2560;
#pragma unroll
            for (int o = 0; o < 5; ++o) wf[o] = *(const short8*)(wp + o * 512);
            short8 pf = *(const short8*)(sbuf +
                ((size_t)(wr + ky) * PD + (wc0 + kx + l31)) * 16 + quad * 8);
#pragma unroll
            for (int o = 0; o < 5; ++o)
                acc[o] = __builtin_amdgcn_mfma_f32_32x32x16_bf16(wf[o], pf, acc[o], 0, 0, 0);
        }
    }

    // ---- epilogue: direct coalesced stores (px = lane&31 = contiguous cols) ----
    const size_t imgBase = (size_t)bj * OFFC * (IM * IM);
    const size_t rowAddr = imgBase + (size_t)(y0 + wr) * IM + wc0 + l31;
#pragma unroll
    for (int o = 0; o < 5; ++o) {
        const int rmax = (o == 4) ? 8 : 16;
#pragma unroll
        for (int r = 0; r < 16; ++r) {
            if (r >= rmax) break;
            int oc = o * 32 + (r & 3) + 8 * (r >> 2) + 4 * quad;
            float v = acc[o][r] + bias[oc];
            size_t a = rowAddr + (size_t)oc * (IM * IM);
            if (MODE == 1) v += addend[a];
            out[a] = v;
        }
    }
}

// ---------------- bilinear 2x upsample * 2.0 ----------------
__global__ void upsample_k(const float* __restrict__ off2, float* __restrict__ off2u) {
    int idx = blockIdx.x * 256 + threadIdx.x;  // < 18874368
    int ox = idx & 127;
    int oy = (idx >> 7) & 127;
    int p = idx >> 14;
    const float* sp = off2 + (size_t)p * HW2;
    float sy = 0.5f * oy - 0.25f;
    float sx = 0.5f * ox - 0.25f;
    float y0f = floorf(sy), x0f = floorf(sx);
    int y0 = (int)y0f, x0 = (int)x0f;
    float fy = sy - y0f, fx = sx - x0f;
    int y0c = max(y0, 0), y1c = min(y0 + 1, 63);
    int x0c = max(x0, 0), x1c = min(x0 + 1, 63);
    float v00 = sp[y0c * 64 + x0c], v01 = sp[y0c * 64 + x1c];
    float v10 = sp[y1c * 64 + x0c], v11 = sp[y1c * 64 + x1c];
    float v = v00 * (1.f - fy) * (1.f - fx) + v01 * (1.f - fy) * fx +
              v10 * fy * (1.f - fx) + v11 * fy * fx;
    off2u[idx] = 2.0f * v;
}

// ---------------- deformable conv (3x3, G=8 offset groups), MFMA phase B -------------
// block = 256 thr (4 waves) per 32-px row segment.
// outMode 0: write z1 as padded NHWC-bf16 chunk planes; outMode 1: NCHW fp32 final out.
#define SROW 584
__global__ __launch_bounds__(256, 4) void dconv_k(
    const float* __restrict__ x,    // (B,T,C,H,W)
    const float* __restrict__ off,  // (BJ,144,H,W)
    const short* __restrict__ wsw,  // swizzled B-frags [chunk36][tile2][lane64][8]
    float* __restrict__ out, short* __restrict__ z1T, int outMode) {
    const int bj = blockIdx.y;
    const int b = bj >> 2;
    const int j = bj & 3;
    const int i = j + (j >= 2 ? 1 : 0);
    const int seg = blockIdx.x;  // 0..511
    const int y = seg >> 2;
    const int x0 = (seg & 3) << 5;
    const int tid = threadIdx.x;

    __shared__ short sS[32 * SROW];  // 37376 B; reused as float Pbuf[4][32][33]
    float* Pbuf = (float*)sS;

    const float* xin = x + (size_t)(b * TT + i) * CC * HW;
    const float* offp = off + (size_t)bj * OFFC * HW + y * WW + x0;

    // ---- phase A: bilinear sampling into LDS ----
    {
        const int g = tid >> 5;   // 0..7 offset group
        const int px = tid & 31;
        short* srow = sS + px * SROW + g * 72;
#pragma unroll
        for (int k = 0; k < 9; ++k) {
            float dy = offp[(size_t)((g * 9 + k) * 2) * HW + px];
            float dx = offp[(size_t)((g * 9 + k) * 2 + 1) * HW + px];
            const int kyy = k / 3 - 1;
            const int kxx = k % 3 - 1;
            float sy = (float)(y + kyy) + dy;
            float sx = (float)(x0 + px + kxx) + dx;
            float y0f = floorf(sy), x0f = floorf(sx);
            int iy = (int)y0f, ix = (int)x0f;
            float wy = sy - y0f, wx = sx - x0f;
            bool yv0 = (iy >= 0) & (iy < HH);
            bool yv1 = (iy + 1 >= 0) & (iy + 1 < HH);
            bool xv0 = (ix >= 0) & (ix < WW);
            bool xv1 = (ix + 1 >= 0) & (ix + 1 < WW);
            float w00 = (yv0 && xv0) ? (1.f - wy) * (1.f - wx) : 0.f;
            float w01 = (yv0 && xv1) ? (1.f - wy) * wx : 0.f;
            float w10 = (yv1 && xv0) ? wy * (1.f - wx) : 0.f;
            float w11 = (yv1 && xv1) ? wy * wx : 0.f;
            int iy0 = min(max(iy, 0), HH - 1);
            int iy1 = min(max(iy + 1, 0), HH - 1);
            int ix0 = min(max(ix, 0), WW - 1);
            int ix1 = min(max(ix + 1, 0), WW - 1);
            int o00 = iy0 * WW + ix0, o01 = iy0 * WW + ix1;
            int o10 = iy1 * WW + ix0, o11 = iy1 * WW + ix1;
            const float* xp = xin + (size_t)(g * 8) * HW;
#pragma unroll 4
            for (int c = 0; c < 8; ++c) {
                float v = xp[o00] * w00 + xp[o01] * w01 + xp[o10] * w10 + xp[o11] * w11;
                srow[c * 9 + k] = (short)f2bf(v);
                xp += HW;
            }
        }
    }
    __syncthreads();

    // ---- phase B: C[px 32][oc 64] = S * W, K=576, MFMA 32x32x16 ----
    const int wv = tid >> 6;      // wave 0..3
    const int lane = tid & 63;
    const int tile = wv >> 1;     // oc tile
    const int kw = wv & 1;        // K half
    floatx16 acc;
#pragma unroll
    for (int g = 0; g < 16; ++g) acc[g] = 0.f;

    const short* aBase = sS + (lane & 31) * SROW + (lane >> 5) * 8;
    const short* bBase = wsw + ((size_t)tile * 64 + lane) * 8;
    for (int chunk = kw * 18; chunk < kw * 18 + 18; ++chunk) {
        short8 af = *(const short8*)(aBase + chunk * 16);
        short8 bf = *(const short8*)(bBase + (size_t)chunk * 1024);
        acc = __builtin_amdgcn_mfma_f32_32x32x16_bf16(af, bf, acc, 0, 0, 0);
    }

    __syncthreads();  // all waves done reading sS
    {
        const int n = lane & 31;
#pragma unroll
        for (int g = 0; g < 16; ++g) {
            int m = (g & 3) + 8 * (g >> 2) + 4 * (lane >> 5);
            Pbuf[wv * 1056 + m * 33 + n] = acc[g];
        }
    }
    __syncthreads();

    // ---- epilogue: reduce K-halves, store ----
    if (outMode == 0) {
        // write padded NHWC-bf16 chunk planes: [bj][chunk(4)][132][132][16]
        const int chunk = tid >> 6;
        const int px = (tid >> 1) & 31;
        const int half = tid & 1;
        const int t2 = chunk >> 1;
        const int n0 = (chunk & 1) * 16 + half * 8;
        short8 sv;
#pragma unroll
        for (int q = 0; q < 8; ++q) {
            float v = Pbuf[(t2 * 2) * 1056 + px * 33 + n0 + q] +
                      Pbuf[(t2 * 2 + 1) * 1056 + px * 33 + n0 + q];
            sv[q] = (short)f2bf(v);
        }
        *(short8*)&z1T[((size_t)bj * 4 + chunk) * PLANE1 +
                       ((size_t)(y + 2) * 132 + (x0 + 2 + px)) * 16 + half * 8] = sv;
    } else {
        const size_t planeBase = (size_t)(b * TT + i) * CC * HW;
        const size_t rowBase = planeBase + (size_t)y * WW + x0;
#pragma unroll
        for (int rep = 0; rep < 8; ++rep) {
            int elem = rep * 256 + tid;
            int oc = elem >> 5;
            int px = elem & 31;
            int t = oc >> 5;
            int n = oc & 31;
            float v = Pbuf[(t * 2) * 1056 + px * 33 + n] +
                      Pbuf[(t * 2 + 1) * 1056 + px * 33 + n];
            out[rowBase + (size_t)oc * HW + px] = v;
        }
    }
}

// ---------------- center frame passthrough ----------------
__global__ void copy_center_k(const float* __restrict__ x, float* __restrict__ out) {
    int idx = blockIdx.x * 256 + threadIdx.x;  // < 524288 float4s
    int b = idx >> 18;
    int rem = idx & 262143;
    size_t o = (((size_t)(b * TT + TCF) * CC * HW) >> 2) + rem;
    ((float4*)out)[o] = ((const float4*)x)[o];
}

extern "C" void kernel_launch(void* const* d_in, const int* in_sizes, int n_in,
                              void* d_out, int out_size, void* d_ws, size_t ws_size,
                              hipStream_t stream) {
    const float* x = (const float*)d_in[0];
    const float* w_off1 = (const float*)d_in[1];
    const float* b_off1 = (const float*)d_in[2];
    const float* w_off2 = (const float*)d_in[3];
    const float* b_off2 = (const float*)d_in[4];
    const float* w_align1 = (const float*)d_in[5];
    const float* w_alignf = (const float*)d_in[6];
    float* out = (float*)d_out;
    float* ws = (float*)d_ws;

    float* off2 = ws;                        // 4,718,592 floats (NCHW fp32)
    float* off2u = ws + 4718592;             // 18,874,368
    float* off1 = ws + 23592960;             // 18,874,368
    short* z1T = (short*)(ws + 42467328);    // 8,921,088 shorts (4,460,544 fl)
    short* xT = (short*)(ws + 46927872);     // 2,230,272 shorts (1,115,136 fl)
    short* x2T = (short*)(ws + 48043008);    // 2,787,840 shorts (1,393,920 fl)
    short* wsD1 = (short*)(ws + 49436928);   // 36,864 shorts
    short* wsDf = (short*)(ws + 49455360);   // 36,864 shorts
    short* w2s = (short*)(ws + 49473792);    // 184,320 shorts
    short* w1s = (short*)(ws + 49565952);    // 512,000 shorts

    // zero the padded NHWC plane buffers (z1T, xT, x2T are contiguous)
    hipMemsetAsync((void*)z1T, 0, 27878400, stream);

    wswzD_k<<<144, 256, 0, stream>>>(w_align1, wsD1);
    wswzD_k<<<144, 256, 0, stream>>>(w_alignf, wsDf);
    wswz_k<9><<<720, 256, 0, stream>>>(w_off2, w2s);
    wswz_k<25><<<2000, 256, 0, stream>>>(w_off1, w1s);

    avgpool_k<<<dim3(64, 4, 10), 256, 0, stream>>>(x, x2T);
    xtrans_k<<<dim3(128, 4, 2), 256, 0, stream>>>(x, xT);

    convmf_k<0><<<dim3(16, 1, 8), 512, 0, stream>>>(x2T, x2T, w2s, b_off2,
                                                    nullptr, off2);
    upsample_k<<<73728, 256, 0, stream>>>(off2, off2u);
    dconv_k<<<dim3(512, 8), 256, 0, stream>>>(x, off2u, wsD1, nullptr, z1T, 0);
    convmf_k<1><<<dim3(64, 1, 8), 512, 0, stream>>>(z1T, xT, w1s, b_off1,
                                                    off2u, off1);
    dconv_k<<<dim3(512, 8), 256, 0, stream>>>(x, off1, wsDf, out, nullptr, 1);
    copy_center_k<<<2048, 256, 0, stream>>>(x, out);
}